// Round 1
// baseline (80.374 us; speedup 1.0000x reference)
//
#include <hip/hip_runtime.h>

#define NKC 256   // clusters (K)
#define ND  64    // feature dim (D)
#define BM  64    // rows per block

using v8bf = __attribute__((ext_vector_type(8))) __bf16;
using v4f  = __attribute__((ext_vector_type(4))) float;
using v4u  = __attribute__((ext_vector_type(4))) unsigned int;

__device__ __forceinline__ unsigned short f2bf(float f) {
    // round-to-nearest-even f32 -> bf16 (inputs are finite normals; no NaN path)
    unsigned int x = __float_as_uint(f);
    x += 0x7FFFu + ((x >> 16) & 1u);
    return (unsigned short)(x >> 16);
}

// Convert clusters (256x64 f32) to bf16 + per-row sum of squares, into workspace.
// 64 blocks x 256 threads: each wave handles one cluster row (64 elems = 64 lanes).
__global__ void prep_kernel(const float* __restrict__ clusters,
                            unsigned short* __restrict__ cbf,
                            float* __restrict__ csq) {
    int t = threadIdx.x;
    int lane = t & 63;
    int row = blockIdx.x * 4 + (t >> 6);
    float v = clusters[row * ND + lane];
    cbf[row * ND + lane] = f2bf(v);
    float p = v * v;
#pragma unroll
    for (int m = 1; m <= 32; m <<= 1) p += __shfl_xor(p, m);
    if (lane == 0) csq[row] = p;
}

__global__ __launch_bounds__(256)
void cluster_kernel(const float* __restrict__ x,
                    const unsigned short* __restrict__ cbf,
                    const float* __restrict__ csq,
                    float* __restrict__ out) {
    // LDS: bf16 x-tile + bf16 clusters, XOR-swizzled (row stride 128B = G4 conflict case)
    __shared__ __align__(16) unsigned short sx[BM * ND];    // 8 KB
    __shared__ __align__(16) unsigned short sc[NKC * ND];   // 32 KB
    __shared__ float sxsq[BM];
    __shared__ float scsq[NKC];

    const int t = threadIdx.x;
    const int bid = blockIdx.x;

    // ---- stage x tile: 64 rows x 64 dims, f32 -> bf16, plus row sum-of-squares
    {
        const int row = t >> 2;            // 0..63
        const int d0  = (t & 3) << 4;      // 0,16,32,48
        const v4f* src = reinterpret_cast<const v4f*>(
            x + (size_t)(bid * BM + row) * ND + d0);
        v4f v0 = src[0], v1 = src[1], v2 = src[2], v3 = src[3];
        float vv[16];
        *(v4f*)&vv[0]  = v0; *(v4f*)&vv[4]  = v1;
        *(v4f*)&vv[8]  = v2; *(v4f*)&vv[12] = v3;
        float p = 0.f;
#pragma unroll
        for (int i = 0; i < 16; ++i) p += vv[i] * vv[i];
        p += __shfl_xor(p, 1);
        p += __shfl_xor(p, 2);
        if ((t & 3) == 0) sxsq[row] = p;
        v4u w0, w1;
#pragma unroll
        for (int i = 0; i < 4; ++i) {
            w0[i] = (unsigned)f2bf(vv[2*i])     | ((unsigned)f2bf(vv[2*i+1]) << 16);
            w1[i] = (unsigned)f2bf(vv[8+2*i])   | ((unsigned)f2bf(vv[9+2*i]) << 16);
        }
        const int swz = (row & 7) << 4;
        const int byte0 = row * 128 + d0 * 2;
        char* base = (char*)sx;
        *(v4u*)(base + ( byte0        ^ swz)) = w0;
        *(v4u*)(base + ((byte0 + 16)  ^ swz)) = w1;
    }

    // ---- stage clusters (256x64 bf16 = 32KB) from workspace, swizzled
    {
        char* dst = (char*)sc;
        const char* src = (const char*)cbf;
#pragma unroll
        for (int i = 0; i < 8; ++i) {
            int idx16 = t + i * 256;           // 16B chunk index, coalesced
            int byte  = idx16 << 4;
            int crow  = byte >> 7;             // /128
            v4u val = *(const v4u*)(src + byte);
            *(v4u*)(dst + (byte ^ ((crow & 7) << 4))) = val;
        }
        scsq[t] = csq[t];
    }
    __syncthreads();

    const int lane = t & 63;
    const int wid  = t >> 6;            // 4 waves, each owns 16 rows
    const int wrow = wid << 4;
    const int lr   = lane & 15;
    const int kg   = (lane >> 4) << 3;  // k-offset within 32: 0,8,16,24

    // A fragments (both k-steps of D=64), from swizzled LDS
    const int arow = wrow + lr;
    const int aswz = (arow & 7) << 4;
    v8bf a0 = *(v8bf*)((char*)sx + ((arow * 128      + kg * 2) ^ aswz));
    v8bf a1 = *(v8bf*)((char*)sx + ((arow * 128 + 64 + kg * 2) ^ aswz));

    v4f acc[16];
#pragma unroll
    for (int j = 0; j < 16; ++j) {
        const int brow = (j << 4) + lr;           // cluster index (col)
        const int bswz = (brow & 7) << 4;
        v8bf b0 = *(v8bf*)((char*)sc + ((brow * 128      + kg * 2) ^ bswz));
        v8bf b1 = *(v8bf*)((char*)sc + ((brow * 128 + 64 + kg * 2) ^ bswz));
        v4f c = {0.f, 0.f, 0.f, 0.f};
        c = __builtin_amdgcn_mfma_f32_16x16x32_bf16(a0, b0, c, 0, 0, 0);
        c = __builtin_amdgcn_mfma_f32_16x16x32_bf16(a1, b1, c, 0, 0, 0);
        acc[j] = c;
    }

    // ---- epilogue: u = 1/(1+d), row-sum over K via 16-lane shuffle reduce, normalize
    // C/D layout (HW-verified): col = lane&15, row = (lane>>4)*4 + reg
    const int rbase = wrow + ((lane >> 4) << 2);
    float xs[4];
#pragma unroll
    for (int r = 0; r < 4; ++r) xs[r] = sxsq[rbase + r];

    float ps[4] = {0.f, 0.f, 0.f, 0.f};
#pragma unroll
    for (int j = 0; j < 16; ++j) {
        const float cs = scsq[(j << 4) + lr];
#pragma unroll
        for (int r = 0; r < 4; ++r) {
            float d = xs[r] + cs - 2.0f * acc[j][r];
            float u = __builtin_amdgcn_rcpf(1.0f + d);
            acc[j][r] = u;
            ps[r] += u;
        }
    }
#pragma unroll
    for (int m = 1; m <= 8; m <<= 1) {
#pragma unroll
        for (int r = 0; r < 4; ++r) ps[r] += __shfl_xor(ps[r], m);
    }
    float inv[4];
#pragma unroll
    for (int r = 0; r < 4; ++r) inv[r] = __builtin_amdgcn_rcpf(ps[r]);

    float* orow = out + (size_t)(bid * BM + rbase) * NKC + lr;
#pragma unroll
    for (int j = 0; j < 16; ++j) {
#pragma unroll
        for (int r = 0; r < 4; ++r) {
            orow[(size_t)r * NKC + (j << 4)] = acc[j][r] * inv[r];
        }
    }
}

extern "C" void kernel_launch(void* const* d_in, const int* in_sizes, int n_in,
                              void* d_out, int out_size, void* d_ws, size_t ws_size,
                              hipStream_t stream) {
    const float* x        = (const float*)d_in[0];
    const float* clusters = (const float*)d_in[1];
    float* out = (float*)d_out;
    const int N = in_sizes[0] / ND;                 // 262144

    unsigned short* cbf = (unsigned short*)d_ws;                         // 32 KB
    float* csq = (float*)((char*)d_ws + (size_t)NKC * ND * sizeof(unsigned short)); // 1 KB

    prep_kernel<<<NKC / 4, 256, 0, stream>>>(clusters, cbf, csq);
    cluster_kernel<<<N / BM, 256, 0, stream>>>(x, cbf, csq, out);
}